// Round 1
// baseline (6285.350 us; speedup 1.0000x reference)
//
#include <hip/hip_runtime.h>
#include <hip/hip_bf16.h>

#define B_ 256
#define T_ 500
#define I_ 256
#define H_ 512
#define G_ 2048   // 4*H
#define O_ 100

typedef __attribute__((ext_vector_type(8))) short short8;   // 8 x bf16 fragment (4 VGPR)
typedef __attribute__((ext_vector_type(4))) float f32x4;    // MFMA accumulator

// ---- workspace layout (bytes) ----
#define WHB_OFF 0u                              // Wh as bf16   [2048][512]  2 MB
#define WXB_OFF (G_*H_*2u)                      // Wx as bf16   [2048][256]  1 MB
#define BSUM_OFF (WXB_OFF + G_*I_*2u)           // bx+bh f32    [2048]       8 KB
#define H0_OFF  (BSUM_OFF + G_*4u)              // h buf 0 bf16 [256][512]   256 KB
#define H1_OFF  (H0_OFF + B_*H_*2u)             // h buf 1 bf16               256 KB
#define C_OFF   (H1_OFF + B_*H_*2u)             // c f32        [256][512]   512 KB
#define HT_OFF  (C_OFF + B_*H_*4u)              // final h f32  [256][512]   512 KB
// total ~4.5 MB

__device__ __forceinline__ float sigm(float v) { return 1.0f / (1.0f + __expf(-v)); }
__device__ __forceinline__ float tanh_fast(float v) { return 2.0f / (1.0f + __expf(-2.0f * v)) - 1.0f; }

__device__ __forceinline__ short f2bf_s(float f) {
  union { __hip_bfloat16 h; unsigned short u; } cv;
  cv.h = __float2bfloat16(f);
  return (short)cv.u;
}

// Cast weights to bf16 once per call; precompute bias sum.
__global__ void cast_kernel(const float* __restrict__ Wh, const float* __restrict__ Wx,
                            const float* __restrict__ bx, const float* __restrict__ bh,
                            short* __restrict__ Whb, short* __restrict__ Wxb,
                            float* __restrict__ bsum) {
  int idx = blockIdx.x * 256 + threadIdx.x;
  if (idx < G_ * H_) Whb[idx] = f2bf_s(Wh[idx]);
  if (idx < G_ * I_) Wxb[idx] = f2bf_s(Wx[idx]);
  if (idx < G_)      bsum[idx] = bx[idx] + bh[idx];
}

// One LSTM timestep, fused: gates = [h, x_t] @ [Wh, Wx].T + (bx+bh); cell update.
// Grid: (32 cell-chunks of 16 cells, 8 batch-chunks of 32 rows). Block: 128 (2 waves).
// Each wave computes a 16x64 gate tile = four 16x16 MFMA tiles (one per gate type),
// so each lane ends up holding i,f,g,o for the same (row, cell) -> local cell update.
__global__ __launch_bounds__(128)
void lstm_step(const float* __restrict__ x, int t,
               const short* __restrict__ Whb, const short* __restrict__ Wxb,
               const float* __restrict__ bsum,
               const short* __restrict__ h_in,
               unsigned short* __restrict__ h_out,
               float* __restrict__ c,
               float* __restrict__ hT) {
  const int lane = threadIdx.x & 63;
  const int w    = threadIdx.x >> 6;
  const int r    = lane & 15;          // A-row / B-col / D-col selector
  const int ko   = (lane >> 4) << 3;   // k offset within a K=32 chunk (8 elems/lane)
  const int brow = blockIdx.y * 32 + w * 16;
  const int cbase = blockIdx.x * 16;

  f32x4 acc[4];
  #pragma unroll
  for (int q = 0; q < 4; ++q) { acc[q][0] = 0.f; acc[q][1] = 0.f; acc[q][2] = 0.f; acc[q][3] = 0.f; }

  // ---- K part 1: previous h (bf16), K = 0..511 ----
  const short* ha = h_in + (size_t)(brow + r) * H_ + ko;
  #pragma unroll 4
  for (int kk = 0; kk < H_; kk += 32) {
    short8 a = *reinterpret_cast<const short8*>(ha + kk);
    #pragma unroll
    for (int q = 0; q < 4; ++q) {
      const short* bp = Whb + (size_t)(q * H_ + cbase + r) * H_ + kk + ko;
      short8 b = *reinterpret_cast<const short8*>(bp);
      acc[q] = __builtin_amdgcn_mfma_f32_16x16x32_bf16(a, b, acc[q], 0, 0, 0);
    }
  }

  // ---- K part 2: x_t (f32 -> bf16 in-register), K = 512..767 ----
  const float* xrow = x + ((size_t)(brow + r) * T_ + t) * I_ + ko;
  #pragma unroll 2
  for (int kk = 0; kk < I_; kk += 32) {
    float4 x0 = *reinterpret_cast<const float4*>(xrow + kk);
    float4 x1 = *reinterpret_cast<const float4*>(xrow + kk + 4);
    short8 a;
    a[0] = f2bf_s(x0.x); a[1] = f2bf_s(x0.y); a[2] = f2bf_s(x0.z); a[3] = f2bf_s(x0.w);
    a[4] = f2bf_s(x1.x); a[5] = f2bf_s(x1.y); a[6] = f2bf_s(x1.z); a[7] = f2bf_s(x1.w);
    #pragma unroll
    for (int q = 0; q < 4; ++q) {
      const short* bp = Wxb + (size_t)(q * H_ + cbase + r) * I_ + kk + ko;
      short8 b = *reinterpret_cast<const short8*>(bp);
      acc[q] = __builtin_amdgcn_mfma_f32_16x16x32_bf16(a, b, acc[q], 0, 0, 0);
    }
  }

  // ---- bias ----
  #pragma unroll
  for (int q = 0; q < 4; ++q) {
    float bb = bsum[q * H_ + cbase + r];
    acc[q][0] += bb; acc[q][1] += bb; acc[q][2] += bb; acc[q][3] += bb;
  }

  // ---- cell update: lane holds i,f,g,o for (row_j, cell), j=0..3 ----
  const int cell = cbase + r;          // D col = lane&15
  #pragma unroll
  for (int j = 0; j < 4; ++j) {
    const int row = brow + ((lane >> 4) << 2) + j;   // D row = (lane>>4)*4 + j
    const size_t ci = (size_t)row * H_ + cell;
    float ig = sigm(acc[0][j]);
    float fg = sigm(acc[1][j]);
    float gg = tanh_fast(acc[2][j]);
    float og = sigm(acc[3][j]);
    float cn = c[ci] * fg + ig * gg;
    c[ci] = cn;
    float hn = og * tanh_fast(cn);
    h_out[ci] = (unsigned short)f2bf_s(hn);
    if (hT) hT[ci] = hn;               // f32 final h for the FC epilogue
  }
}

// out[b][o] = hT[b,:] . Wfc[o,:] + bfc[o]
__global__ __launch_bounds__(128)
void fc_kernel(const float* __restrict__ hT, const float* __restrict__ Wfc,
               const float* __restrict__ bfc, float* __restrict__ out) {
  int b = blockIdx.x;
  int o = threadIdx.x;
  if (o >= O_) return;
  const float* hr = hT + (size_t)b * H_;
  const float* wr = Wfc + (size_t)o * H_;
  float s = 0.f;
  #pragma unroll 4
  for (int k = 0; k < H_; k += 4) {
    float4 hv = *reinterpret_cast<const float4*>(hr + k);
    float4 wv = *reinterpret_cast<const float4*>(wr + k);
    s += hv.x * wv.x + hv.y * wv.y + hv.z * wv.z + hv.w * wv.w;
  }
  out[b * O_ + o] = s + bfc[o];
}

extern "C" void kernel_launch(void* const* d_in, const int* in_sizes, int n_in,
                              void* d_out, int out_size, void* d_ws, size_t ws_size,
                              hipStream_t stream) {
  const float* x   = (const float*)d_in[0];
  const float* Wx  = (const float*)d_in[1];
  const float* bx  = (const float*)d_in[2];
  const float* Wh  = (const float*)d_in[3];
  const float* bh  = (const float*)d_in[4];
  const float* Wfc = (const float*)d_in[5];
  const float* bfc = (const float*)d_in[6];
  float* out = (float*)d_out;
  char* ws = (char*)d_ws;

  short* Whb  = (short*)(ws + WHB_OFF);
  short* Wxb  = (short*)(ws + WXB_OFF);
  float* bsum = (float*)(ws + BSUM_OFF);
  short* h0   = (short*)(ws + H0_OFF);
  short* h1   = (short*)(ws + H1_OFF);
  float* cbuf = (float*)(ws + C_OFF);
  float* hT   = (float*)(ws + HT_OFF);

  // h0 = 0 (bf16 zeros are bit-zeros), c0 = 0
  hipMemsetAsync(ws + H0_OFF, 0, B_ * H_ * 2, stream);
  hipMemsetAsync(ws + C_OFF,  0, B_ * H_ * 4, stream);

  cast_kernel<<<(G_ * H_ + 255) / 256, 256, 0, stream>>>(Wh, Wx, bx, bh, Whb, Wxb, bsum);

  for (int t = 0; t < T_; ++t) {
    const short* hin = (t & 1) ? h1 : h0;
    unsigned short* hout = (unsigned short*)((t & 1) ? h0 : h1);
    lstm_step<<<dim3(32, 8), 128, 0, stream>>>(x, t, Whb, Wxb, bsum, hin, hout, cbuf,
                                               (t == T_ - 1) ? hT : nullptr);
  }

  fc_kernel<<<B_, 128, 0, stream>>>(hT, Wfc, bfc, out);
}